// Round 1
// baseline (201.515 us; speedup 1.0000x reference)
//
#include <hip/hip_runtime.h>
#include <hip/hip_bf16.h>
#include <math.h>

#define N_ 8192
#define D_ 256

typedef __attribute__((ext_vector_type(8))) short bf16x8;
typedef __attribute__((ext_vector_type(4))) float f32x4;
typedef __attribute__((ext_vector_type(8))) unsigned short u16x8;

__device__ __forceinline__ unsigned short f2bf(float f) {
    unsigned int u = __float_as_uint(f);
    u += 0x7FFFu + ((u >> 16) & 1u);   // RNE
    return (unsigned short)(u >> 16);
}

__device__ __forceinline__ float softplus_dev(float p) {
    return log1pf(__expf(p));
}

// ---------------------------------------------------------------------------
// Kernel A: out = x + noise*sqrt(v); sq[row] = ||x_row||^2; optional bf16 cast
// of x into ws; zero S2/S8 accumulators. One wave per row, 4 rows per block.
// ---------------------------------------------------------------------------
template<bool WRITE_XB>
__global__ __launch_bounds__(256) void prep_kernel(
    const float* __restrict__ x, const float* __restrict__ noise,
    const float* __restrict__ phi, float* __restrict__ out,
    float* __restrict__ sq, unsigned short* __restrict__ xb,
    float* __restrict__ S2, float* __restrict__ S8)
{
    const int wave = threadIdx.x >> 6;
    const int lane = threadIdx.x & 63;
    const int row  = blockIdx.x * 4 + wave;

    const float v  = softplus_dev(phi[0]);
    const float sv = sqrtf(v);

    const int base = row * D_ + lane * 4;
    const float4 xv = *(const float4*)&x[base];
    const float4 nv = *(const float4*)&noise[base];

    float4 ov;
    ov.x = xv.x + nv.x * sv;
    ov.y = xv.y + nv.y * sv;
    ov.z = xv.z + nv.z * sv;
    ov.w = xv.w + nv.w * sv;
    *(float4*)&out[base] = ov;

    if (WRITE_XB) {
        ushort4 bv;
        bv.x = f2bf(xv.x); bv.y = f2bf(xv.y);
        bv.z = f2bf(xv.z); bv.w = f2bf(xv.w);
        *(ushort4*)&xb[base] = bv;
    }

    float s = xv.x*xv.x + xv.y*xv.y + xv.z*xv.z + xv.w*xv.w;
    #pragma unroll
    for (int off = 1; off < 64; off <<= 1)
        s += __shfl_xor(s, off, 64);

    if (lane == 0) {
        sq[row] = s;
        S2[row] = 0.0f;
        S8[row] = 0.0f;
    }
}

// ---------------------------------------------------------------------------
// Kernel B: G = Xb * Xb^T tiled 128x128 (K chunked 2x128), fused epilogue:
// dist = sq[i]+sq[j]-2G (clamped, diag forced 0), accumulate
// S2[i] += sum_j exp(-dist/(2v)), S8[i] += sum_j exp(-dist/(8v)).
// 256 threads = 4 waves in a 2x2 grid, each wave owns a 64x64 sub-tile
// as 4x4 fragments of v_mfma_f32_16x16x32_bf16.
// ---------------------------------------------------------------------------
constexpr int LDK = 136;   // padded LDS stride (bf16 elems) for 128-col chunk

template<bool USE_XB>
__global__ __launch_bounds__(256) void dist_kernel(
    const float* __restrict__ x, const unsigned short* __restrict__ xb,
    const float* __restrict__ sq, const float* __restrict__ phi,
    float* __restrict__ S2, float* __restrict__ S8)
{
    __shared__ unsigned short As[128 * LDK];
    __shared__ unsigned short Bs[128 * LDK];
    __shared__ float sqA[128];
    __shared__ float sqB[128];

    const int tid = threadIdx.x;
    const int bi = blockIdx.y, bj = blockIdx.x;
    const int i0 = bi * 128, j0 = bj * 128;

    const float v  = softplus_dev(phi[0]);
    const float c2 = -1.0f / (2.0f * v);
    const float c8 = -1.0f / (8.0f * v);

    if (tid < 128) sqA[tid] = sq[i0 + tid];
    else           sqB[tid - 128] = sq[j0 + tid - 128];

    const int lane = tid & 63;
    const int wave = tid >> 6;
    const int wr = wave >> 1, wc = wave & 1;
    const int lr = lane & 15;   // A/B fragment row; C fragment col
    const int lk = lane >> 4;   // k-group / C row-group

    f32x4 acc[4][4];
    #pragma unroll
    for (int m = 0; m < 4; ++m)
        #pragma unroll
        for (int n = 0; n < 4; ++n)
            acc[m][n] = (f32x4){0.f, 0.f, 0.f, 0.f};

    for (int kc = 0; kc < 2; ++kc) {
        __syncthreads();
        if (USE_XB) {
            // 128 rows * 16 chunks(8 bf16) per panel = 2048 chunks / 256 thr
            #pragma unroll
            for (int it = 0; it < 8; ++it) {
                int idx = it * 256 + tid;
                int row = idx >> 4, c = idx & 15;
                u16x8 va = *(const u16x8*)&xb[(size_t)(i0 + row) * D_ + kc * 128 + c * 8];
                *(u16x8*)&As[row * LDK + c * 8] = va;
                u16x8 vb = *(const u16x8*)&xb[(size_t)(j0 + row) * D_ + kc * 128 + c * 8];
                *(u16x8*)&Bs[row * LDK + c * 8] = vb;
            }
        } else {
            // f32 source: 128 rows * 32 float4 per panel = 4096 / 256 thr
            #pragma unroll
            for (int it = 0; it < 16; ++it) {
                int idx = it * 256 + tid;
                int row = idx >> 5, c = idx & 31;
                float4 fa = *(const float4*)&x[(size_t)(i0 + row) * D_ + kc * 128 + c * 4];
                ushort4 ua; ua.x = f2bf(fa.x); ua.y = f2bf(fa.y);
                ua.z = f2bf(fa.z); ua.w = f2bf(fa.w);
                *(ushort4*)&As[row * LDK + c * 4] = ua;
                float4 fb = *(const float4*)&x[(size_t)(j0 + row) * D_ + kc * 128 + c * 4];
                ushort4 ub; ub.x = f2bf(fb.x); ub.y = f2bf(fb.y);
                ub.z = f2bf(fb.z); ub.w = f2bf(fb.w);
                *(ushort4*)&Bs[row * LDK + c * 4] = ub;
            }
        }
        __syncthreads();

        #pragma unroll
        for (int k = 0; k < 4; ++k) {
            bf16x8 af[4], bfr[4];
            #pragma unroll
            for (int m = 0; m < 4; ++m) {
                int r = wr * 64 + m * 16 + lr;
                af[m] = *(const bf16x8*)&As[r * LDK + k * 32 + lk * 8];
            }
            #pragma unroll
            for (int n = 0; n < 4; ++n) {
                int r = wc * 64 + n * 16 + lr;
                bfr[n] = *(const bf16x8*)&Bs[r * LDK + k * 32 + lk * 8];
            }
            #pragma unroll
            for (int m = 0; m < 4; ++m)
                #pragma unroll
                for (int n = 0; n < 4; ++n)
                    acc[m][n] = __builtin_amdgcn_mfma_f32_16x16x32_bf16(
                        af[m], bfr[n], acc[m][n], 0, 0, 0);
        }
    }

    // Epilogue: dist -> exp -> per-row partial sums -> atomics.
    // C fragment mapping: col = lane&15, row = (lane>>4)*4 + reg   [m89]
    #pragma unroll
    for (int m = 0; m < 4; ++m) {
        #pragma unroll
        for (int r = 0; r < 4; ++r) {
            int li = wr * 64 + m * 16 + lk * 4 + r;
            int gi = i0 + li;
            float si = sqA[li];
            float sum2 = 0.f, sum8 = 0.f;
            #pragma unroll
            for (int n = 0; n < 4; ++n) {
                int lj = wc * 64 + n * 16 + lr;
                int gj = j0 + lj;
                float g = acc[m][n][r];
                float dd = si + sqB[lj] - 2.0f * g;
                dd = fmaxf(dd, 0.0f);
                if (gi == gj) dd = 0.0f;
                sum2 += __expf(dd * c2);
                sum8 += __expf(dd * c8);
            }
            #pragma unroll
            for (int off = 1; off < 16; off <<= 1) {
                sum2 += __shfl_xor(sum2, off, 64);
                sum8 += __shfl_xor(sum8, off, 64);
            }
            if (lr == 0) {
                atomicAdd(&S2[gi], sum2);
                atomicAdd(&S8[gi], sum8);
            }
        }
    }
}

// ---------------------------------------------------------------------------
// Kernel C: finalize scalars.
// ---------------------------------------------------------------------------
__global__ __launch_bounds__(256) void finalize_kernel(
    const float* __restrict__ S2, const float* __restrict__ S8,
    const float* __restrict__ sq, const float* __restrict__ phi,
    const float* __restrict__ priorv, float* __restrict__ outs)
{
    float l2 = 0.f, l8 = 0.f, ss = 0.f;
    for (int i = threadIdx.x; i < N_; i += 256) {
        l2 += logf(S2[i]);
        l8 += logf(S8[i]);
        ss += sq[i];
    }
    #pragma unroll
    for (int off = 1; off < 64; off <<= 1) {
        l2 += __shfl_xor(l2, off, 64);
        l8 += __shfl_xor(l8, off, 64);
        ss += __shfl_xor(ss, off, 64);
    }
    __shared__ float r2[4], r8[4], rs[4];
    const int wave = threadIdx.x >> 6, lane = threadIdx.x & 63;
    if (lane == 0) { r2[wave] = l2; r8[wave] = l8; rs[wave] = ss; }
    __syncthreads();
    if (threadIdx.x == 0) {
        float L2 = r2[0] + r2[1] + r2[2] + r2[3];
        float L8 = r8[0] + r8[1] + r8[2] + r8[3];
        float SS = rs[0] + rs[1] + rs[2] + rs[3];
        float v = softplus_dev(phi[0]);
        float p = priorv[0];
        float logN = logf((float)N_);
        // lower bound: denom=8v ; upper: denom=2v ; gmm const - H cancels to logN
        outs[0] = logN - L8 / (float)N_;                       // Ixt_lb
        outs[1] = logN - L2 / (float)N_;                       // Ixt
        outs[2] = (float)D_ * (0.5f * logf(p / v) + v / (2.0f * p) - 0.5f)
                  + SS / (2.0f * p * (float)N_);               // vIxt
    }
}

// ---------------------------------------------------------------------------
extern "C" void kernel_launch(void* const* d_in, const int* in_sizes, int n_in,
                              void* d_out, int out_size, void* d_ws, size_t ws_size,
                              hipStream_t stream) {
    const float* x     = (const float*)d_in[0];
    const float* noise = (const float*)d_in[1];
    const float* phi   = (const float*)d_in[2];
    const float* prior = (const float*)d_in[3];

    float* out  = (float*)d_out;
    float* scal = out + (size_t)N_ * D_;

    char* ws = (char*)d_ws;
    const size_t xb_bytes = (size_t)N_ * D_ * sizeof(unsigned short);
    const size_t red_bytes = 3 * (size_t)N_ * sizeof(float);
    const bool useXb = ws_size >= xb_bytes + red_bytes;

    unsigned short* xb = (unsigned short*)ws;
    float* sq = useXb ? (float*)(ws + xb_bytes) : (float*)ws;
    float* S2 = sq + N_;
    float* S8 = S2 + N_;

    if (useXb)
        prep_kernel<true><<<N_ / 4, 256, 0, stream>>>(x, noise, phi, out, sq, xb, S2, S8);
    else
        prep_kernel<false><<<N_ / 4, 256, 0, stream>>>(x, noise, phi, out, sq, xb, S2, S8);

    dim3 grid(N_ / 128, N_ / 128);
    if (useXb)
        dist_kernel<true><<<grid, 256, 0, stream>>>(x, xb, sq, phi, S2, S8);
    else
        dist_kernel<false><<<grid, 256, 0, stream>>>(x, xb, sq, phi, S2, S8);

    finalize_kernel<<<1, 256, 0, stream>>>(S2, S8, sq, phi, prior, scal);
}

// Round 2
// 91.972 us; speedup vs baseline: 2.1911x; 2.1911x over previous
//
#include <hip/hip_runtime.h>
#include <hip/hip_bf16.h>
#include <math.h>

#define N_ 8192
#define D_ 256
#define NTILE 64                        // N_/128
#define NBLK (NTILE*(NTILE+1)/2)        // 2080 upper-triangular blocks

typedef __attribute__((ext_vector_type(8))) short bf16x8;
typedef __attribute__((ext_vector_type(4))) float f32x4;
typedef __attribute__((ext_vector_type(8))) unsigned short u16x8;

__device__ __forceinline__ unsigned short f2bf(float f) {
    unsigned int u = __float_as_uint(f);
    u += 0x7FFFu + ((u >> 16) & 1u);   // RNE
    return (unsigned short)(u >> 16);
}

__device__ __forceinline__ float softplus_dev(float p) {
    return log1pf(__expf(p));
}

__device__ __forceinline__ void gload_lds16(const void* g, void* l) {
    __builtin_amdgcn_global_load_lds(
        (const __attribute__((address_space(1))) unsigned int*)g,
        (__attribute__((address_space(3))) unsigned int*)l,
        16, 0, 0);
}

// ---------------------------------------------------------------------------
// Kernel A: out = x + noise*sqrt(v); sq[row] = ||x_row||^2; optional bf16 cast
// of x into ws; zero S2/S8 accumulators. One wave per row, 4 rows per block.
// ---------------------------------------------------------------------------
template<bool WRITE_XB>
__global__ __launch_bounds__(256) void prep_kernel(
    const float* __restrict__ x, const float* __restrict__ noise,
    const float* __restrict__ phi, float* __restrict__ out,
    float* __restrict__ sq, unsigned short* __restrict__ xb,
    float* __restrict__ S2, float* __restrict__ S8)
{
    const int wave = threadIdx.x >> 6;
    const int lane = threadIdx.x & 63;
    const int row  = blockIdx.x * 4 + wave;

    const float v  = softplus_dev(phi[0]);
    const float sv = sqrtf(v);

    const int base = row * D_ + lane * 4;
    const float4 xv = *(const float4*)&x[base];
    const float4 nv = *(const float4*)&noise[base];

    float4 ov;
    ov.x = xv.x + nv.x * sv;
    ov.y = xv.y + nv.y * sv;
    ov.z = xv.z + nv.z * sv;
    ov.w = xv.w + nv.w * sv;
    *(float4*)&out[base] = ov;

    if (WRITE_XB) {
        ushort4 bv;
        bv.x = f2bf(xv.x); bv.y = f2bf(xv.y);
        bv.z = f2bf(xv.z); bv.w = f2bf(xv.w);
        *(ushort4*)&xb[base] = bv;
    }

    float s = xv.x*xv.x + xv.y*xv.y + xv.z*xv.z + xv.w*xv.w;
    #pragma unroll
    for (int off = 1; off < 64; off <<= 1)
        s += __shfl_xor(s, off, 64);

    if (lane == 0) {
        sq[row] = s;
        S2[row] = 0.0f;
        S8[row] = 0.0f;
    }
}

// ---------------------------------------------------------------------------
// Kernel B: upper-triangular 128x128 blocks of G = Xb*Xb^T, K in 4 chunks of
// 64, global_load_lds staging with XOR-swizzled source (rule #21), fused
// epilogue: dist -> e8=exp(-d/8v), e2=e8^4; row-sums -> S[i], col-sums -> S[j]
// (off-diag only, symmetry). 4 waves, each 4x4 frags of 16x16x32 MFMA.
// ---------------------------------------------------------------------------
template<bool USE_XB>
__global__ __launch_bounds__(256) void dist_kernel(
    const float* __restrict__ x, const unsigned short* __restrict__ xb,
    const float* __restrict__ sq, const float* __restrict__ phi,
    float* __restrict__ S2, float* __restrict__ S8)
{
    __shared__ unsigned short As[128 * 64];   // 16 KB, linear, XOR-swizzled data
    __shared__ unsigned short Bs[128 * 64];   // 16 KB
    __shared__ float sqA[128];
    __shared__ float sqB[128];

    const int tid  = threadIdx.x;
    const int lane = tid & 63;
    const int wave = tid >> 6;

    // triangular block decode: t -> (bi, bj), bj >= bi
    int t  = (int)blockIdx.x;
    int bi = (int)((129.0f - sqrtf(129.0f * 129.0f - 8.0f * (float)t)) * 0.5f);
    while ((bi + 1) * (129 - (bi + 1)) / 2 <= t) ++bi;
    while (bi * (129 - bi) / 2 > t) --bi;
    const int bj = bi + (t - bi * (129 - bi) / 2);
    const int i0 = bi * 128, j0 = bj * 128;
    const bool diag = (bi == bj);

    const float v  = softplus_dev(phi[0]);
    const float c8 = -1.0f / (8.0f * v);

    if (tid < 128) sqA[tid] = sq[i0 + tid];
    else           sqB[tid - 128] = sq[j0 + tid - 128];

    const int wr = wave >> 1, wc = wave & 1;
    const int lr = lane & 15;
    const int lk = lane >> 4;

    f32x4 acc[4][4];
    #pragma unroll
    for (int m = 0; m < 4; ++m)
        #pragma unroll
        for (int n = 0; n < 4; ++n)
            acc[m][n] = (f32x4){0.f, 0.f, 0.f, 0.f};

    for (int kc = 0; kc < 4; ++kc) {
        if (USE_XB) {
            #pragma unroll
            for (int it = 0; it < 4; ++it) {
                int s    = it * 256 + tid;
                int row  = s >> 3;                 // 8 x 16B slots per 128B row
                int cbs  = (s & 7) * 16;           // linear byte-in-row
                int srcb = cbs ^ ((row & 7) << 4); // pre-swizzled source pos
                const size_t ga = (size_t)(i0 + row) * D_ + kc * 64 + (srcb >> 1);
                const size_t gb = (size_t)(j0 + row) * D_ + kc * 64 + (srcb >> 1);
                char* la = (char*)As + (it * 256 + wave * 64) * 16;
                char* lb = (char*)Bs + (it * 256 + wave * 64) * 16;
                gload_lds16(&xb[ga], la);
                gload_lds16(&xb[gb], lb);
            }
        } else {
            #pragma unroll
            for (int it = 0; it < 4; ++it) {
                int s    = it * 256 + tid;
                int row  = s >> 3;
                int e0   = (s & 7) * 8;            // bf16 elems within chunk
                int dstb = (row * 128 + (s & 7) * 16) ^ ((row & 7) << 4);
                {
                    const float* src = &x[(size_t)(i0 + row) * D_ + kc * 64 + e0];
                    float4 f0 = *(const float4*)src;
                    float4 f1 = *(const float4*)(src + 4);
                    u16x8 u;
                    u[0] = f2bf(f0.x); u[1] = f2bf(f0.y); u[2] = f2bf(f0.z); u[3] = f2bf(f0.w);
                    u[4] = f2bf(f1.x); u[5] = f2bf(f1.y); u[6] = f2bf(f1.z); u[7] = f2bf(f1.w);
                    *(u16x8*)((char*)As + dstb) = u;
                }
                {
                    const float* src = &x[(size_t)(j0 + row) * D_ + kc * 64 + e0];
                    float4 f0 = *(const float4*)src;
                    float4 f1 = *(const float4*)(src + 4);
                    u16x8 u;
                    u[0] = f2bf(f0.x); u[1] = f2bf(f0.y); u[2] = f2bf(f0.z); u[3] = f2bf(f0.w);
                    u[4] = f2bf(f1.x); u[5] = f2bf(f1.y); u[6] = f2bf(f1.z); u[7] = f2bf(f1.w);
                    *(u16x8*)((char*)Bs + dstb) = u;
                }
            }
        }
        __syncthreads();   // drains vmcnt (gload_lds) / lgkm (ds_write)

        #pragma unroll
        for (int k = 0; k < 2; ++k) {
            bf16x8 af[4], bv[4];
            #pragma unroll
            for (int m = 0; m < 4; ++m) {
                int r  = wr * 64 + m * 16 + lr;
                int ab = (r * 128 + k * 64 + lk * 16) ^ ((r & 7) << 4);
                af[m] = *(const bf16x8*)((const char*)As + ab);
            }
            #pragma unroll
            for (int n = 0; n < 4; ++n) {
                int r  = wc * 64 + n * 16 + lr;
                int ab = (r * 128 + k * 64 + lk * 16) ^ ((r & 7) << 4);
                bv[n] = *(const bf16x8*)((const char*)Bs + ab);
            }
            #pragma unroll
            for (int m = 0; m < 4; ++m)
                #pragma unroll
                for (int n = 0; n < 4; ++n)
                    acc[m][n] = __builtin_amdgcn_mfma_f32_16x16x32_bf16(
                        af[m], bv[n], acc[m][n], 0, 0, 0);
        }
        __syncthreads();
    }

    // Epilogue. C frag: col = lane&15, row = (lane>>4)*4 + reg   [m89]
    float cs2[4] = {0.f, 0.f, 0.f, 0.f};
    float cs8[4] = {0.f, 0.f, 0.f, 0.f};
    #pragma unroll
    for (int m = 0; m < 4; ++m) {
        #pragma unroll
        for (int r = 0; r < 4; ++r) {
            int li = wr * 64 + m * 16 + lk * 4 + r;
            int gi = i0 + li;
            float si = sqA[li];
            float rs2 = 0.f, rs8 = 0.f;
            #pragma unroll
            for (int n = 0; n < 4; ++n) {
                int lj = wc * 64 + n * 16 + lr;
                float g = acc[m][n][r];
                float dd = si + sqB[lj] - 2.0f * g;
                dd = fmaxf(dd, 0.0f);
                if (diag && li == lj) dd = 0.0f;
                float e8 = __expf(dd * c8);
                float e4 = e8 * e8;
                float e2 = e4 * e4;      // exp(dd*c2) since c2 = 4*c8
                rs2 += e2; rs8 += e8;
                cs2[n] += e2; cs8[n] += e8;
            }
            #pragma unroll
            for (int off = 1; off < 16; off <<= 1) {
                rs2 += __shfl_xor(rs2, off, 64);
                rs8 += __shfl_xor(rs8, off, 64);
            }
            if (lr == 0) {
                atomicAdd(&S2[gi], rs2);
                atomicAdd(&S8[gi], rs8);
            }
        }
    }
    if (!diag) {   // symmetric contribution to rows j0.. via column sums
        #pragma unroll
        for (int n = 0; n < 4; ++n) {
            float v2 = cs2[n], v8 = cs8[n];
            v2 += __shfl_xor(v2, 16, 64); v2 += __shfl_xor(v2, 32, 64);
            v8 += __shfl_xor(v8, 16, 64); v8 += __shfl_xor(v8, 32, 64);
            if (lk == 0) {
                int gj = j0 + wc * 64 + n * 16 + lr;
                atomicAdd(&S2[gj], v2);
                atomicAdd(&S8[gj], v8);
            }
        }
    }
}

// ---------------------------------------------------------------------------
// Kernel C: finalize scalars. 1024 threads, one block.
// ---------------------------------------------------------------------------
__global__ __launch_bounds__(1024) void finalize_kernel(
    const float* __restrict__ S2, const float* __restrict__ S8,
    const float* __restrict__ sq, const float* __restrict__ phi,
    const float* __restrict__ priorv, float* __restrict__ outs)
{
    float l2 = 0.f, l8 = 0.f, ss = 0.f;
    for (int i = threadIdx.x; i < N_; i += 1024) {
        l2 += logf(S2[i]);
        l8 += logf(S8[i]);
        ss += sq[i];
    }
    #pragma unroll
    for (int off = 1; off < 64; off <<= 1) {
        l2 += __shfl_xor(l2, off, 64);
        l8 += __shfl_xor(l8, off, 64);
        ss += __shfl_xor(ss, off, 64);
    }
    __shared__ float r2[16], r8[16], rs[16];
    const int wave = threadIdx.x >> 6, lane = threadIdx.x & 63;
    if (lane == 0) { r2[wave] = l2; r8[wave] = l8; rs[wave] = ss; }
    __syncthreads();
    if (threadIdx.x == 0) {
        float L2 = 0.f, L8 = 0.f, SS = 0.f;
        for (int w = 0; w < 16; ++w) { L2 += r2[w]; L8 += r8[w]; SS += rs[w]; }
        float v = softplus_dev(phi[0]);
        float p = priorv[0];
        float logN = logf((float)N_);
        outs[0] = logN - L8 / (float)N_;                       // Ixt_lb
        outs[1] = logN - L2 / (float)N_;                       // Ixt
        outs[2] = (float)D_ * (0.5f * logf(p / v) + v / (2.0f * p) - 0.5f)
                  + SS / (2.0f * p * (float)N_);               // vIxt
    }
}

// ---------------------------------------------------------------------------
extern "C" void kernel_launch(void* const* d_in, const int* in_sizes, int n_in,
                              void* d_out, int out_size, void* d_ws, size_t ws_size,
                              hipStream_t stream) {
    const float* x     = (const float*)d_in[0];
    const float* noise = (const float*)d_in[1];
    const float* phi   = (const float*)d_in[2];
    const float* prior = (const float*)d_in[3];

    float* out  = (float*)d_out;
    float* scal = out + (size_t)N_ * D_;

    char* ws = (char*)d_ws;
    const size_t xb_bytes  = (size_t)N_ * D_ * sizeof(unsigned short);
    const size_t red_bytes = 3 * (size_t)N_ * sizeof(float);
    const bool useXb = ws_size >= xb_bytes + red_bytes;

    unsigned short* xb = (unsigned short*)ws;
    float* sq = useXb ? (float*)(ws + xb_bytes) : (float*)ws;
    float* S2 = sq + N_;
    float* S8 = S2 + N_;

    if (useXb)
        prep_kernel<true><<<N_ / 4, 256, 0, stream>>>(x, noise, phi, out, sq, xb, S2, S8);
    else
        prep_kernel<false><<<N_ / 4, 256, 0, stream>>>(x, noise, phi, out, sq, xb, S2, S8);

    if (useXb)
        dist_kernel<true><<<NBLK, 256, 0, stream>>>(x, xb, sq, phi, S2, S8);
    else
        dist_kernel<false><<<NBLK, 256, 0, stream>>>(x, xb, sq, phi, S2, S8);

    finalize_kernel<<<1, 1024, 0, stream>>>(S2, S8, sq, phi, prior, scal);
}

// Round 3
// 86.811 us; speedup vs baseline: 2.3213x; 1.0595x over previous
//
#include <hip/hip_runtime.h>
#include <hip/hip_bf16.h>
#include <math.h>

#define N_ 8192
#define D_ 256
#define NTILE 64                        // N_/128
#define NBLK (NTILE*(NTILE+1)/2)        // 2080 upper-triangular blocks

typedef __attribute__((ext_vector_type(8))) short bf16x8;
typedef __attribute__((ext_vector_type(4))) float f32x4;
typedef __attribute__((ext_vector_type(8))) unsigned short u16x8;

__device__ __forceinline__ unsigned short f2bf(float f) {
    unsigned int u = __float_as_uint(f);
    u += 0x7FFFu + ((u >> 16) & 1u);   // RNE
    return (unsigned short)(u >> 16);
}

__device__ __forceinline__ float softplus_dev(float p) {
    return log1pf(__expf(p));
}

__device__ __forceinline__ void gload_lds16(const void* g, void* l) {
    __builtin_amdgcn_global_load_lds(
        (const __attribute__((address_space(1))) unsigned int*)g,
        (__attribute__((address_space(3))) unsigned int*)l,
        16, 0, 0);
}

// ---------------------------------------------------------------------------
// Kernel A: out = x + noise*sqrt(v); sq[row] = ||x_row||^2; bf16 cast of x
// into ws; zero S2/S8. One wave per row, 4 rows per block.
// ---------------------------------------------------------------------------
template<bool WRITE_XB>
__global__ __launch_bounds__(256) void prep_kernel(
    const float* __restrict__ x, const float* __restrict__ noise,
    const float* __restrict__ phi, float* __restrict__ out,
    float* __restrict__ sq, unsigned short* __restrict__ xb,
    float* __restrict__ S2, float* __restrict__ S8)
{
    const int wave = threadIdx.x >> 6;
    const int lane = threadIdx.x & 63;
    const int row  = blockIdx.x * 4 + wave;

    const float v  = softplus_dev(phi[0]);
    const float sv = sqrtf(v);

    const int base = row * D_ + lane * 4;
    const float4 xv = *(const float4*)&x[base];
    const float4 nv = *(const float4*)&noise[base];

    float4 ov;
    ov.x = xv.x + nv.x * sv;
    ov.y = xv.y + nv.y * sv;
    ov.z = xv.z + nv.z * sv;
    ov.w = xv.w + nv.w * sv;
    *(float4*)&out[base] = ov;

    if (WRITE_XB) {
        ushort4 bv;
        bv.x = f2bf(xv.x); bv.y = f2bf(xv.y);
        bv.z = f2bf(xv.z); bv.w = f2bf(xv.w);
        *(ushort4*)&xb[base] = bv;
    }

    float s = xv.x*xv.x + xv.y*xv.y + xv.z*xv.z + xv.w*xv.w;
    #pragma unroll
    for (int off = 1; off < 64; off <<= 1)
        s += __shfl_xor(s, off, 64);

    if (lane == 0) {
        sq[row] = s;
        S2[row] = 0.0f;
        S8[row] = 0.0f;
    }
}

// ---------------------------------------------------------------------------
// Kernel B: upper-triangular 128x128 blocks of G = Xb*Xb^T.
// BK=32, 8 chunks, DOUBLE-BUFFERED with counted vmcnt (T3/T4): never drain
// to 0 in the loop. LDS layout: paired rows — panel = [64 lrows][8 slots of
// 16B]; slot colp = col ^ (lrow&7); orig (row R, k-octet lk) lives at
// lrow=R>>1, col=((R&1)<<2)|lk. 2-way bank pattern on ds_read_b128 (free).
// gload_lds keeps dest linear; source carries the inverse swizzle (rule 21).
// Fused epilogue: dist -> e8, e2=e8^4; row sums -> S[i]; col sums -> S[j].
// ---------------------------------------------------------------------------
template<bool USE_XB>
__global__ __launch_bounds__(256, 4) void dist_kernel(
    const float* __restrict__ x, const unsigned short* __restrict__ xb,
    const float* __restrict__ sq, const float* __restrict__ phi,
    float* __restrict__ S2, float* __restrict__ S8)
{
    __shared__ unsigned short As[2][4096];   // 2 x 8KB
    __shared__ unsigned short Bs[2][4096];   // 2 x 8KB
    __shared__ float sqA[128];
    __shared__ float sqB[128];

    const int tid  = threadIdx.x;
    const int lane = tid & 63;
    const int wave = tid >> 6;

    // triangular block decode: t -> (bi, bj), bj >= bi
    int t  = (int)blockIdx.x;
    int bi = (int)((129.0f - sqrtf(129.0f * 129.0f - 8.0f * (float)t)) * 0.5f);
    while ((bi + 1) * (129 - (bi + 1)) / 2 <= t) ++bi;
    while (bi * (129 - bi) / 2 > t) --bi;
    const int bj = bi + (t - bi * (129 - bi) / 2);
    const int i0 = bi * 128, j0 = bj * 128;
    const bool diag = (bi == bj);

    const float v  = softplus_dev(phi[0]);
    const float c8 = -1.0f / (8.0f * v);

    if (tid < 128) sqA[tid] = sq[i0 + tid];
    else           sqB[tid - 128] = sq[j0 + tid - 128];

    const int wr = wave >> 1, wc = wave & 1;
    const int lr = lane & 15;
    const int lk = lane >> 4;

    f32x4 acc[4][4];
    #pragma unroll
    for (int m = 0; m < 4; ++m)
        #pragma unroll
        for (int n = 0; n < 4; ++n)
            acc[m][n] = (f32x4){0.f, 0.f, 0.f, 0.f};

    // ---- staging helpers (inlined via lambdas) ----
    // slot s (0..511): lrow=s>>3, colp=s&7; col=colp^(lrow&7);
    // orig row = (lrow<<1)|(col>>2); k-octet = col&3.
    auto stage_xb = [&](int kc, int buf) {
        #pragma unroll
        for (int it = 0; it < 2; ++it) {
            int wbase = it * 256 + wave * 64;       // uniform slot base
            int s     = wbase + lane;
            int lrow  = s >> 3, colp = s & 7;
            int col   = colp ^ (lrow & 7);
            int orow  = (lrow << 1) | (col >> 2);
            int k8    = col & 3;
            size_t off = (size_t)kc * 32 + k8 * 8;
            gload_lds16(&xb[(size_t)(i0 + orow) * D_ + off],
                        (char*)As[buf] + wbase * 16);
            gload_lds16(&xb[(size_t)(j0 + orow) * D_ + off],
                        (char*)Bs[buf] + wbase * 16);
        }
    };
    auto stage_f32 = [&](int kc, int buf) {
        #pragma unroll
        for (int it = 0; it < 2; ++it) {
            int s    = it * 256 + tid;
            int lrow = s >> 3, colp = s & 7;
            int col  = colp ^ (lrow & 7);
            int orow = (lrow << 1) | (col >> 2);
            int k8   = col & 3;
            {
                const float* src = &x[(size_t)(i0 + orow) * D_ + kc * 32 + k8 * 8];
                float4 f0 = *(const float4*)src;
                float4 f1 = *(const float4*)(src + 4);
                u16x8 u;
                u[0] = f2bf(f0.x); u[1] = f2bf(f0.y); u[2] = f2bf(f0.z); u[3] = f2bf(f0.w);
                u[4] = f2bf(f1.x); u[5] = f2bf(f1.y); u[6] = f2bf(f1.z); u[7] = f2bf(f1.w);
                *(u16x8*)((char*)As[buf] + s * 16) = u;
            }
            {
                const float* src = &x[(size_t)(j0 + orow) * D_ + kc * 32 + k8 * 8];
                float4 f0 = *(const float4*)src;
                float4 f1 = *(const float4*)(src + 4);
                u16x8 u;
                u[0] = f2bf(f0.x); u[1] = f2bf(f0.y); u[2] = f2bf(f0.z); u[3] = f2bf(f0.w);
                u[4] = f2bf(f1.x); u[5] = f2bf(f1.y); u[6] = f2bf(f1.z); u[7] = f2bf(f1.w);
                *(u16x8*)((char*)Bs[buf] + s * 16) = u;
            }
        }
    };
    auto compute_chunk = [&](int buf) {
        bf16x8 af[4], bv[4];
        #pragma unroll
        for (int m = 0; m < 4; ++m) {
            int R    = wr * 64 + m * 16 + lr;
            int lrow = R >> 1;
            int colp = (((R & 1) << 2) | lk) ^ (lrow & 7);
            af[m] = *(const bf16x8*)((const char*)As[buf] + lrow * 128 + colp * 16);
        }
        #pragma unroll
        for (int n = 0; n < 4; ++n) {
            int R    = wc * 64 + n * 16 + lr;
            int lrow = R >> 1;
            int colp = (((R & 1) << 2) | lk) ^ (lrow & 7);
            bv[n] = *(const bf16x8*)((const char*)Bs[buf] + lrow * 128 + colp * 16);
        }
        #pragma unroll
        for (int m = 0; m < 4; ++m)
            #pragma unroll
            for (int n = 0; n < 4; ++n)
                acc[m][n] = __builtin_amdgcn_mfma_f32_16x16x32_bf16(
                    af[m], bv[n], acc[m][n], 0, 0, 0);
    };

    if (USE_XB) {
        // -------- T3/T4 pipelined main loop: 8 chunks, 2 buffers --------
        stage_xb(0, 0);
        #pragma unroll
        for (int c = 0; c < 8; ++c) {
            const int cur = c & 1;
            if (c < 7) {
                stage_xb(c + 1, cur ^ 1);
                asm volatile("s_waitcnt vmcnt(4)" ::: "memory");  // chunk c landed
            } else {
                asm volatile("s_waitcnt vmcnt(0)" ::: "memory");
            }
            __builtin_amdgcn_s_barrier();
            compute_chunk(cur);
            if (c < 7) __builtin_amdgcn_s_barrier();  // protect buf reuse
        }
    } else {
        // -------- fallback: single-buffered, full syncs --------
        for (int c = 0; c < 8; ++c) {
            __syncthreads();
            stage_f32(c, 0);
            __syncthreads();
            compute_chunk(0);
        }
    }

    // Epilogue. C frag: col = lane&15, row = (lane>>4)*4 + reg   [m89]
    float cs2[4] = {0.f, 0.f, 0.f, 0.f};
    float cs8[4] = {0.f, 0.f, 0.f, 0.f};
    #pragma unroll
    for (int m = 0; m < 4; ++m) {
        #pragma unroll
        for (int r = 0; r < 4; ++r) {
            int li = wr * 64 + m * 16 + lk * 4 + r;
            int gi = i0 + li;
            float si = sqA[li];
            float rs2 = 0.f, rs8 = 0.f;
            #pragma unroll
            for (int n = 0; n < 4; ++n) {
                int lj = wc * 64 + n * 16 + lr;
                float g = acc[m][n][r];
                float dd = si + sqB[lj] - 2.0f * g;
                dd = fmaxf(dd, 0.0f);
                if (diag && li == lj) dd = 0.0f;
                float e8 = __expf(dd * c8);
                float e4 = e8 * e8;
                float e2 = e4 * e4;      // exp(dd*c2) since c2 = 4*c8
                rs2 += e2; rs8 += e8;
                cs2[n] += e2; cs8[n] += e8;
            }
            #pragma unroll
            for (int off = 1; off < 16; off <<= 1) {
                rs2 += __shfl_xor(rs2, off, 64);
                rs8 += __shfl_xor(rs8, off, 64);
            }
            if (lr == 0) {
                atomicAdd(&S2[gi], rs2);
                atomicAdd(&S8[gi], rs8);
            }
        }
    }
    if (!diag) {   // symmetric contribution to rows j0.. via column sums
        #pragma unroll
        for (int n = 0; n < 4; ++n) {
            float v2 = cs2[n], v8 = cs8[n];
            v2 += __shfl_xor(v2, 16, 64); v2 += __shfl_xor(v2, 32, 64);
            v8 += __shfl_xor(v8, 16, 64); v8 += __shfl_xor(v8, 32, 64);
            if (lk == 0) {
                int gj = j0 + wc * 64 + n * 16 + lr;
                atomicAdd(&S2[gj], v2);
                atomicAdd(&S8[gj], v8);
            }
        }
    }
}

// ---------------------------------------------------------------------------
// Kernel C: finalize scalars. 1024 threads, one block.
// ---------------------------------------------------------------------------
__global__ __launch_bounds__(1024) void finalize_kernel(
    const float* __restrict__ S2, const float* __restrict__ S8,
    const float* __restrict__ sq, const float* __restrict__ phi,
    const float* __restrict__ priorv, float* __restrict__ outs)
{
    float l2 = 0.f, l8 = 0.f, ss = 0.f;
    for (int i = threadIdx.x; i < N_; i += 1024) {
        l2 += logf(S2[i]);
        l8 += logf(S8[i]);
        ss += sq[i];
    }
    #pragma unroll
    for (int off = 1; off < 64; off <<= 1) {
        l2 += __shfl_xor(l2, off, 64);
        l8 += __shfl_xor(l8, off, 64);
        ss += __shfl_xor(ss, off, 64);
    }
    __shared__ float r2[16], r8[16], rs[16];
    const int wave = threadIdx.x >> 6, lane = threadIdx.x & 63;
    if (lane == 0) { r2[wave] = l2; r8[wave] = l8; rs[wave] = ss; }
    __syncthreads();
    if (threadIdx.x == 0) {
        float L2 = 0.f, L8 = 0.f, SS = 0.f;
        for (int w = 0; w < 16; ++w) { L2 += r2[w]; L8 += r8[w]; SS += rs[w]; }
        float v = softplus_dev(phi[0]);
        float p = priorv[0];
        float logN = logf((float)N_);
        outs[0] = logN - L8 / (float)N_;                       // Ixt_lb
        outs[1] = logN - L2 / (float)N_;                       // Ixt
        outs[2] = (float)D_ * (0.5f * logf(p / v) + v / (2.0f * p) - 0.5f)
                  + SS / (2.0f * p * (float)N_);               // vIxt
    }
}

// ---------------------------------------------------------------------------
extern "C" void kernel_launch(void* const* d_in, const int* in_sizes, int n_in,
                              void* d_out, int out_size, void* d_ws, size_t ws_size,
                              hipStream_t stream) {
    const float* x     = (const float*)d_in[0];
    const float* noise = (const float*)d_in[1];
    const float* phi   = (const float*)d_in[2];
    const float* prior = (const float*)d_in[3];

    float* out  = (float*)d_out;
    float* scal = out + (size_t)N_ * D_;

    char* ws = (char*)d_ws;
    const size_t xb_bytes  = (size_t)N_ * D_ * sizeof(unsigned short);
    const size_t red_bytes = 3 * (size_t)N_ * sizeof(float);
    const bool useXb = ws_size >= xb_bytes + red_bytes;

    unsigned short* xb = (unsigned short*)ws;
    float* sq = useXb ? (float*)(ws + xb_bytes) : (float*)ws;
    float* S2 = sq + N_;
    float* S8 = S2 + N_;

    if (useXb)
        prep_kernel<true><<<N_ / 4, 256, 0, stream>>>(x, noise, phi, out, sq, xb, S2, S8);
    else
        prep_kernel<false><<<N_ / 4, 256, 0, stream>>>(x, noise, phi, out, sq, xb, S2, S8);

    if (useXb)
        dist_kernel<true><<<NBLK, 256, 0, stream>>>(x, xb, sq, phi, S2, S8);
    else
        dist_kernel<false><<<NBLK, 256, 0, stream>>>(x, xb, sq, phi, S2, S8);

    finalize_kernel<<<1, 1024, 0, stream>>>(S2, S8, sq, phi, prior, scal);
}